// Round 7
// baseline (263.977 us; speedup 1.0000x reference)
//
#include <hip/hip_runtime.h>
#include <hip/hip_fp16.h>
#include <hip/hip_cooperative_groups.h>
#include <math.h>

namespace cg = cooperative_groups;

// Problem constants
#define BB    16
#define TT    2048
#define VOCAB 14
#define TOKD  8
#define POSD  8
#define DM    16      // TOKD + POSD
#define NH    2
#define HD    3
#define AD    6       // NH*HD
#define FFND  3

#define NTOK  (BB*TT)            // 32768
#define BH    (BB*NH)            // 32
#define TPB   36                 // tiles per bh: sum_{s=0..7}(s+1)
#define NTILE (BH*TPB)           // 1152 tiles, all equal cost

struct P {
    const int*   idx;
    const float* tok_emb;
    const float* pos_enc;
    const float* Wq;
    const float* Wk;
    const float* Wv;
    const float* Wo;
    const float* ln1w;
    const float* ln1b;
    const float* ln2w;
    const float* ln2b;
    const float* lnfw;
    const float* lnfb;
    const float* W1;
    const float* b1;
    const float* W2;
    const float* b2;
    const float* Wh;
    float*       out;
    float*       qbuf;   // [BH][TT] float4 (prescaled q)
    uint4*       kvh;    // [BH][TT] 16B f16 records {k0,k1,k2,v0,v1,v2,_,_}
    float4*      pbuf;   // [BH][TT][8] chunk partials {a0,a1,a2,l}
};

// ---------------------------------------------------------------------------
// Phase 1: per-token prep (gather+concat, LN1, Q/K/V matvecs, pack KV f16)
// ---------------------------------------------------------------------------
__device__ __forceinline__ void do_prep(int gid, const P& p) {
    if (gid >= NTOK) return;
    int t = gid & (TT - 1);
    int b = gid >> 11;

    float x[DM];
    int tok = p.idx[gid];
    #pragma unroll
    for (int j = 0; j < TOKD; ++j) x[j]        = p.tok_emb[tok * TOKD + j];
    #pragma unroll
    for (int j = 0; j < POSD; ++j) x[TOKD + j] = p.pos_enc[t * POSD + j];

    float m = 0.f;
    #pragma unroll
    for (int j = 0; j < DM; ++j) m += x[j];
    m *= (1.f / DM);
    float v = 0.f;
    #pragma unroll
    for (int j = 0; j < DM; ++j) { float d = x[j] - m; v += d * d; }
    v *= (1.f / DM);
    float rs = rsqrtf(v + 1e-5f);
    float h[DM];
    #pragma unroll
    for (int j = 0; j < DM; ++j)
        h[j] = (x[j] - m) * rs * p.ln1w[j] + p.ln1b[j];

    float q[AD], k[AD], vv[AD];
    #pragma unroll
    for (int a = 0; a < AD; ++a) {
        float sq = 0.f, sk = 0.f, sv = 0.f;
        #pragma unroll
        for (int j = 0; j < 8; ++j) {
            sq = fmaf(p.Wq[a * 8 + j], h[TOKD + j], sq);
            sk = fmaf(p.Wk[a * 8 + j], h[TOKD + j], sk);
            sv = fmaf(p.Wv[a * 8 + j], h[j], sv);
        }
        q[a] = sq; k[a] = sk; vv[a] = sv;
    }

    const float QS = 1.4426950408889634f / 1.7320508075688772f; // log2e/sqrt(HD)
    #pragma unroll
    for (int hh = 0; hh < NH; ++hh) {
        size_t base = (size_t)(b * NH + hh) * TT + t;
        *(float4*)(p.qbuf + base * 4) =
            make_float4(q[hh*3] * QS, q[hh*3+1] * QS, q[hh*3+2] * QS, 0.f);
        __half2 h0 = __floats2half2_rn(k[hh*3],    k[hh*3+1]);
        __half2 h1 = __floats2half2_rn(k[hh*3+2],  vv[hh*3]);
        __half2 h2 = __floats2half2_rn(vv[hh*3+1], vv[hh*3+2]);
        uint4 rec;
        rec.x = *reinterpret_cast<unsigned int*>(&h0);
        rec.y = *reinterpret_cast<unsigned int*>(&h1);
        rec.z = *reinterpret_cast<unsigned int*>(&h2);
        rec.w = 0u;
        p.kvh[base] = rec;
    }
}

// ---------------------------------------------------------------------------
// Phase 2: one attention tile = (bh, 256-query super-row s, 256-key chunk c),
// c <= s. Wave wv covers keys [c*256+wv*64, +64); lane owns 4 queries.
// One broadcast ds_read_b128 per key serves 256 query*key pairs. Block
// reduction in LDS; one plain float4 partial store per query.
// ---------------------------------------------------------------------------
__device__ __forceinline__ void do_attn(int tile, int tid,
                                        uint4* skv, float4* spart, const P& p) {
    int bh = tile / TPB;
    int r  = tile - bh * TPB;
    int s  = 0;
    while ((s + 1) * (s + 2) / 2 <= r) ++s;
    int c  = r - s * (s + 1) / 2;

    const uint4* gkv = p.kvh + ((size_t)bh * TT + (c << 8));
    __syncthreads();             // protect skv/spart from previous tile
    skv[tid] = gkv[tid];
    __syncthreads();

    int wv   = tid >> 6;
    int lane = tid & 63;
    int qoff = lane << 2;
    const float4* qp = (const float4*)(p.qbuf + ((size_t)bh * TT + (s << 8) + qoff) * 4);
    float4 q0 = qp[0], q1 = qp[1], q2 = qp[2], q3 = qp[3];

    float l0=0.f,a00=0.f,a10=0.f,a20=0.f;
    float l1=0.f,a01=0.f,a11=0.f,a21=0.f;
    float l2=0.f,a02=0.f,a12=0.f,a22=0.f;
    float l3=0.f,a03=0.f,a13=0.f,a23=0.f;

    int kw = wv << 6;

    if (c < s) {
        #pragma unroll 4
        for (int it = 0; it < 64; ++it) {
            uint4 rec = skv[kw + it];
            float2 f0 = __half22float2(*reinterpret_cast<const __half2*>(&rec.x));
            float2 f1 = __half22float2(*reinterpret_cast<const __half2*>(&rec.y));
            float2 f2 = __half22float2(*reinterpret_cast<const __half2*>(&rec.z));
            float k0 = f0.x, k1 = f0.y, k2 = f1.x;
            float v0 = f1.y, v1 = f2.x, v2 = f2.y;
            float pr;
            pr = exp2f(fmaf(q0.x,k0,fmaf(q0.y,k1,q0.z*k2)));
            l0+=pr; a00=fmaf(pr,v0,a00); a10=fmaf(pr,v1,a10); a20=fmaf(pr,v2,a20);
            pr = exp2f(fmaf(q1.x,k0,fmaf(q1.y,k1,q1.z*k2)));
            l1+=pr; a01=fmaf(pr,v0,a01); a11=fmaf(pr,v1,a11); a21=fmaf(pr,v2,a21);
            pr = exp2f(fmaf(q2.x,k0,fmaf(q2.y,k1,q2.z*k2)));
            l2+=pr; a02=fmaf(pr,v0,a02); a12=fmaf(pr,v1,a12); a22=fmaf(pr,v2,a22);
            pr = exp2f(fmaf(q3.x,k0,fmaf(q3.y,k1,q3.z*k2)));
            l3+=pr; a03=fmaf(pr,v0,a03); a13=fmaf(pr,v1,a13); a23=fmaf(pr,v2,a23);
        }
    } else {
        #pragma unroll 4
        for (int it = 0; it < 64; ++it) {
            int kk_rel = kw + it;
            uint4 rec = skv[kw + it];
            float2 f0 = __half22float2(*reinterpret_cast<const __half2*>(&rec.x));
            float2 f1 = __half22float2(*reinterpret_cast<const __half2*>(&rec.y));
            float2 f2 = __half22float2(*reinterpret_cast<const __half2*>(&rec.z));
            float k0 = f0.x, k1 = f0.y, k2 = f1.x;
            float v0 = f1.y, v1 = f2.x, v2 = f2.y;
            float pr;
            pr = exp2f(fmaf(q0.x,k0,fmaf(q0.y,k1,q0.z*k2)));
            pr = (kk_rel <= qoff)     ? pr : 0.f;
            l0+=pr; a00=fmaf(pr,v0,a00); a10=fmaf(pr,v1,a10); a20=fmaf(pr,v2,a20);
            pr = exp2f(fmaf(q1.x,k0,fmaf(q1.y,k1,q1.z*k2)));
            pr = (kk_rel <= qoff + 1) ? pr : 0.f;
            l1+=pr; a01=fmaf(pr,v0,a01); a11=fmaf(pr,v1,a11); a21=fmaf(pr,v2,a21);
            pr = exp2f(fmaf(q2.x,k0,fmaf(q2.y,k1,q2.z*k2)));
            pr = (kk_rel <= qoff + 2) ? pr : 0.f;
            l2+=pr; a02=fmaf(pr,v0,a02); a12=fmaf(pr,v1,a12); a22=fmaf(pr,v2,a22);
            pr = exp2f(fmaf(q3.x,k0,fmaf(q3.y,k1,q3.z*k2)));
            pr = (kk_rel <= qoff + 3) ? pr : 0.f;
            l3+=pr; a03=fmaf(pr,v0,a03); a13=fmaf(pr,v1,a13); a23=fmaf(pr,v2,a23);
        }
    }

    int pb = (wv << 8) + qoff;
    spart[pb + 0] = make_float4(a00, a10, a20, l0);
    spart[pb + 1] = make_float4(a01, a11, a21, l1);
    spart[pb + 2] = make_float4(a02, a12, a22, l2);
    spart[pb + 3] = make_float4(a03, a13, a23, l3);
    __syncthreads();

    float4 p0 = spart[tid];
    float4 p1 = spart[256 + tid];
    float4 p2 = spart[512 + tid];
    float4 p3 = spart[768 + tid];
    float4 acc = make_float4(p0.x+p1.x+p2.x+p3.x, p0.y+p1.y+p2.y+p3.y,
                             p0.z+p1.z+p2.z+p3.z, p0.w+p1.w+p2.w+p3.w);
    p.pbuf[((size_t)bh * TT + (s << 8) + tid) * 8 + c] = acc;
}

// ---------------------------------------------------------------------------
// Phase 3: epilogue (sum partials, normalize, Wo+res, LN2, GELU FFN, res,
// LNf, logits 16->8->14)
// ---------------------------------------------------------------------------
__device__ __forceinline__ void do_epi(int gid, const P& p) {
    if (gid >= NTOK) return;
    int t = gid & (TT - 1);
    int b = gid >> 11;
    int s = t >> 8;

    float x[DM];
    int tok = p.idx[gid];
    #pragma unroll
    for (int j = 0; j < TOKD; ++j) x[j]        = p.tok_emb[tok * TOKD + j];
    #pragma unroll
    for (int j = 0; j < POSD; ++j) x[TOKD + j] = p.pos_enc[t * POSD + j];

    float att[AD];
    #pragma unroll
    for (int hh = 0; hh < NH; ++hh) {
        const float4* pp = p.pbuf + ((size_t)(b * NH + hh) * TT + t) * 8;
        float4 acc = pp[0];
        for (int c = 1; c <= s; ++c) {
            float4 e = pp[c];
            acc.x += e.x; acc.y += e.y; acc.z += e.z; acc.w += e.w;
        }
        float inv = 1.f / acc.w;
        att[hh*3+0] = acc.x * inv;
        att[hh*3+1] = acc.y * inv;
        att[hh*3+2] = acc.z * inv;
    }

    float xo[DM];
    #pragma unroll
    for (int j = 0; j < DM; ++j) {
        float sacc = x[j];
        #pragma unroll
        for (int a = 0; a < AD; ++a) sacc = fmaf(p.Wo[j * AD + a], att[a], sacc);
        xo[j] = sacc;
    }

    float m = 0.f;
    #pragma unroll
    for (int j = 0; j < DM; ++j) m += xo[j];
    m *= (1.f / DM);
    float v = 0.f;
    #pragma unroll
    for (int j = 0; j < DM; ++j) { float d = xo[j] - m; v += d * d; }
    v *= (1.f / DM);
    float rs = rsqrtf(v + 1e-5f);
    float h2[DM];
    #pragma unroll
    for (int j = 0; j < DM; ++j)
        h2[j] = (xo[j] - m) * rs * p.ln2w[j] + p.ln2b[j];

    float g[FFND];
    #pragma unroll
    for (int cc = 0; cc < FFND; ++cc) {
        float f = p.b1[cc];
        #pragma unroll
        for (int j = 0; j < DM; ++j) f = fmaf(p.W1[cc * DM + j], h2[j], f);
        g[cc] = 0.5f * f * (1.f + erff(f * 0.70710678118654752f));
    }
    float x2[DM];
    #pragma unroll
    for (int j = 0; j < DM; ++j) {
        float sacc = xo[j] + p.b2[j];
        #pragma unroll
        for (int cc = 0; cc < FFND; ++cc) sacc = fmaf(p.W2[j * FFND + cc], g[cc], sacc);
        x2[j] = sacc;
    }

    m = 0.f;
    #pragma unroll
    for (int j = 0; j < DM; ++j) m += x2[j];
    m *= (1.f / DM);
    v = 0.f;
    #pragma unroll
    for (int j = 0; j < DM; ++j) { float d = x2[j] - m; v += d * d; }
    v *= (1.f / DM);
    rs = rsqrtf(v + 1e-5f);
    float y[DM];
    #pragma unroll
    for (int j = 0; j < DM; ++j)
        y[j] = (x2[j] - m) * rs * p.lnfw[j] + p.lnfb[j];

    float t8[TOKD];
    #pragma unroll
    for (int pp = 0; pp < TOKD; ++pp) {
        float sacc = 0.f;
        #pragma unroll
        for (int j = 0; j < DM; ++j) sacc = fmaf(p.Wh[pp * DM + j], y[j], sacc);
        t8[pp] = sacc;
    }
    float* op = p.out + (size_t)gid * VOCAB;
    #pragma unroll
    for (int vcb = 0; vcb < VOCAB; ++vcb) {
        float sacc = 0.f;
        #pragma unroll
        for (int pp = 0; pp < TOKD; ++pp)
            sacc = fmaf(t8[pp], p.tok_emb[vcb * TOKD + pp], sacc);
        op[vcb] = sacc;
    }
}

// ---------------------------------------------------------------------------
// Kernels: fused cooperative version + standalone fallback versions.
// ---------------------------------------------------------------------------
__global__ __launch_bounds__(256, 2) void fused_kernel(P p) {
    cg::grid_group grid = cg::this_grid();
    __shared__ uint4  skv[256];      // 4 KB
    __shared__ float4 spart[1024];   // 16 KB
    const int tid = threadIdx.x;

    for (int base = blockIdx.x * 256; base < NTOK; base += gridDim.x * 256)
        do_prep(base + tid, p);
    grid.sync();
    for (int tile = blockIdx.x; tile < NTILE; tile += gridDim.x)
        do_attn(tile, tid, skv, spart, p);
    grid.sync();
    for (int base = blockIdx.x * 256; base < NTOK; base += gridDim.x * 256)
        do_epi(base + tid, p);
}

__global__ __launch_bounds__(256) void prep_kernel(P p) {
    do_prep(blockIdx.x * 256 + threadIdx.x, p);
}
__global__ __launch_bounds__(256) void attn_kernel(P p) {
    __shared__ uint4  skv[256];
    __shared__ float4 spart[1024];
    do_attn(blockIdx.x, threadIdx.x, skv, spart, p);
}
__global__ __launch_bounds__(256) void epi_kernel(P p) {
    do_epi(blockIdx.x * 256 + threadIdx.x, p);
}

// ---------------------------------------------------------------------------
extern "C" void kernel_launch(void* const* d_in, const int* in_sizes, int n_in,
                              void* d_out, int out_size, void* d_ws, size_t ws_size,
                              hipStream_t stream) {
    P p;
    p.idx     = (const int*)d_in[0];
    p.tok_emb = (const float*)d_in[1];
    p.pos_enc = (const float*)d_in[2];
    p.Wq      = (const float*)d_in[3];
    p.Wk      = (const float*)d_in[4];
    p.Wv      = (const float*)d_in[5];
    p.Wo      = (const float*)d_in[6];
    p.ln1w    = (const float*)d_in[7];
    p.ln1b    = (const float*)d_in[8];
    p.ln2w    = (const float*)d_in[9];
    p.ln2b    = (const float*)d_in[10];
    p.lnfw    = (const float*)d_in[11];
    p.lnfb    = (const float*)d_in[12];
    p.W1      = (const float*)d_in[13];
    p.b1      = (const float*)d_in[14];
    p.W2      = (const float*)d_in[15];
    p.b2      = (const float*)d_in[16];
    p.Wh      = (const float*)d_in[17];
    p.out     = (float*)d_out;
    p.qbuf    = (float*)d_ws;                          // 1 MB
    p.kvh     = (uint4*)((char*)d_ws + (1u << 20));    // 1 MB
    p.pbuf    = (float4*)((char*)d_ws + (2u << 20));   // 8 MB

    // Capture-safe host queries to decide cooperative vs fallback.
    int dev = 0;
    hipGetDevice(&dev);
    int coop = 0, ncu = 0, maxb = 0;
    hipDeviceGetAttribute(&coop, hipDeviceAttributeCooperativeLaunch, dev);
    hipDeviceGetAttribute(&ncu, hipDeviceAttributeMultiprocessorCount, dev);
    hipOccupancyMaxActiveBlocksPerMultiprocessor(&maxb, fused_kernel, 256, 0);

    long cap = (long)maxb * (long)ncu;
    if (coop && cap >= 256) {
        int grid = (int)(cap < 1024 ? cap : 1024);
        void* args[] = { (void*)&p };
        hipLaunchCooperativeKernel((void*)fused_kernel, dim3(grid), dim3(256),
                                   args, 0, stream);
    } else {
        prep_kernel<<<NTOK / 256, 256, 0, stream>>>(p);
        attn_kernel<<<NTILE, 256, 0, stream>>>(p);
        epi_kernel<<<NTOK / 256, 256, 0, stream>>>(p);
    }
}

// Round 8
// 135.819 us; speedup vs baseline: 1.9436x; 1.9436x over previous
//
#include <hip/hip_runtime.h>
#include <hip/hip_fp16.h>
#include <math.h>

// Problem constants
#define BB    16
#define TT    2048
#define VOCAB 14
#define TOKD  8
#define POSD  8
#define DM    16      // TOKD + POSD
#define NH    2
#define HD    3
#define AD    6       // NH*HD
#define FFND  3

#define NTOK  (BB*TT)            // 32768
#define BH    (BB*NH)            // 32
#define TPB   36                 // tiles per bh: sum_{s=0..7}(s+1)
#define NTILE (BH*TPB)           // 1152 equal-cost tiles

struct P {
    const int*   idx;
    const float* tok_emb;
    const float* pos_enc;
    const float* Wq;
    const float* Wk;
    const float* Wv;
    const float* Wo;
    const float* ln1w;
    const float* ln1b;
    const float* ln2w;
    const float* ln2b;
    const float* lnfw;
    const float* lnfb;
    const float* W1;
    const float* b1;
    const float* W2;
    const float* b2;
    const float* Wh;
    float*       out;
    float4*      pbuf;   // [BH][8][TT] chunk partials {a0,a1,a2,l}, transposed
};

// LN1 hidden state for token (b, t)
__device__ __forceinline__ void ln1_h(const P& p, int b, int t, float* h) {
    float x[DM];
    int tok = p.idx[b * TT + t];
    #pragma unroll
    for (int j = 0; j < TOKD; ++j) x[j]        = p.tok_emb[tok * TOKD + j];
    #pragma unroll
    for (int j = 0; j < POSD; ++j) x[TOKD + j] = p.pos_enc[t * POSD + j];
    float m = 0.f;
    #pragma unroll
    for (int j = 0; j < DM; ++j) m += x[j];
    m *= (1.f / DM);
    float v = 0.f;
    #pragma unroll
    for (int j = 0; j < DM; ++j) { float d = x[j] - m; v += d * d; }
    v *= (1.f / DM);
    float rs = rsqrtf(v + 1e-5f);
    #pragma unroll
    for (int j = 0; j < DM; ++j)
        h[j] = (x[j] - m) * rs * p.ln1w[j] + p.ln1b[j];
}

// ---------------------------------------------------------------------------
// Kernel A: one block per tile (bh, super-row s of 256 queries, chunk c of
// 256 keys), c <= s. Block SELF-PREPS the KV chunk and the Q row into LDS
// (redundant ~18x but removes all inter-block dependencies/flags/barriers).
// Wave wv covers keys [c*256+wv*64,+64); lane owns queries lane+{0,64,128,192}.
// One broadcast ds_read_b128 per key serves 256 query*key pairs. Block LDS
// reduce; one coalesced float4 partial store per query into transposed pbuf.
// ---------------------------------------------------------------------------
__global__ __launch_bounds__(256) void attn_kernel(P p) {
    __shared__ uint4  skv[256];      // 4 KB: chunk KV, f16-packed
    __shared__ float4 sq[256];       // 4 KB: row Q (prescaled)
    __shared__ float4 spart[1024];   // 16 KB: per-wave partials

    const int tid  = threadIdx.x;
    int tile = blockIdx.x;
    int bh   = tile / TPB;
    int r    = tile - bh * TPB;
    int s    = 0;
    while (((s + 1) * (s + 2)) / 2 <= r) ++s;
    int c    = r - (s * (s + 1)) / 2;
    int b    = bh >> 1, head = bh & 1;

    const float QS = 1.4426950408889634f / 1.7320508075688772f; // log2e/sqrt(HD)

    // ---- self-prep pass 1: chunk-c token -> k,v (and q if diagonal) ----
    {
        int t = (c << 8) + tid;
        float h[DM];
        ln1_h(p, b, t, h);
        float k[HD], v[HD];
        #pragma unroll
        for (int d = 0; d < HD; ++d) {
            int a = head * HD + d;
            float sk = 0.f, sv = 0.f;
            #pragma unroll
            for (int j = 0; j < 8; ++j) {
                sk = fmaf(p.Wk[a * 8 + j], h[TOKD + j], sk);
                sv = fmaf(p.Wv[a * 8 + j], h[j], sv);
            }
            k[d] = sk; v[d] = sv;
        }
        __half2 h0 = __floats2half2_rn(k[0], k[1]);
        __half2 h1 = __floats2half2_rn(k[2], v[0]);
        __half2 h2 = __floats2half2_rn(v[1], v[2]);
        uint4 rec;
        rec.x = *reinterpret_cast<unsigned int*>(&h0);
        rec.y = *reinterpret_cast<unsigned int*>(&h1);
        rec.z = *reinterpret_cast<unsigned int*>(&h2);
        rec.w = 0u;
        skv[tid] = rec;
        if (c == s) {
            float q[HD];
            #pragma unroll
            for (int d = 0; d < HD; ++d) {
                int a = head * HD + d;
                float sqv = 0.f;
                #pragma unroll
                for (int j = 0; j < 8; ++j)
                    sqv = fmaf(p.Wq[a * 8 + j], h[TOKD + j], sqv);
                q[d] = sqv;
            }
            sq[tid] = make_float4(q[0] * QS, q[1] * QS, q[2] * QS, 0.f);
        }
    }
    // ---- self-prep pass 2 (off-diagonal): row-s token -> q ----
    if (c != s) {
        int t = (s << 8) + tid;
        float h[DM];
        ln1_h(p, b, t, h);
        float q[HD];
        #pragma unroll
        for (int d = 0; d < HD; ++d) {
            int a = head * HD + d;
            float sqv = 0.f;
            #pragma unroll
            for (int j = 0; j < 8; ++j)
                sqv = fmaf(p.Wq[a * 8 + j], h[TOKD + j], sqv);
            q[d] = sqv;
        }
        sq[tid] = make_float4(q[0] * QS, q[1] * QS, q[2] * QS, 0.f);
    }
    __syncthreads();

    // ---- attention ----
    int wv   = tid >> 6;
    int lane = tid & 63;
    int kw   = wv << 6;                       // wave's key offset in chunk
    float4 q0 = sq[lane];
    float4 q1 = sq[64 + lane];
    float4 q2 = sq[128 + lane];
    float4 q3 = sq[192 + lane];

    float l0=0.f,a00=0.f,a10=0.f,a20=0.f;
    float l1=0.f,a01=0.f,a11=0.f,a21=0.f;
    float l2=0.f,a02=0.f,a12=0.f,a22=0.f;
    float l3=0.f,a03=0.f,a13=0.f,a23=0.f;

    if (c < s) {
        #pragma unroll 4
        for (int it = 0; it < 64; ++it) {
            uint4 rec = skv[kw + it];
            float2 f0 = __half22float2(*reinterpret_cast<const __half2*>(&rec.x));
            float2 f1 = __half22float2(*reinterpret_cast<const __half2*>(&rec.y));
            float2 f2 = __half22float2(*reinterpret_cast<const __half2*>(&rec.z));
            float k0 = f0.x, k1 = f0.y, k2 = f1.x;
            float v0 = f1.y, v1 = f2.x, v2 = f2.y;
            float pr;
            pr = exp2f(fmaf(q0.x,k0,fmaf(q0.y,k1,q0.z*k2)));
            l0+=pr; a00=fmaf(pr,v0,a00); a10=fmaf(pr,v1,a10); a20=fmaf(pr,v2,a20);
            pr = exp2f(fmaf(q1.x,k0,fmaf(q1.y,k1,q1.z*k2)));
            l1+=pr; a01=fmaf(pr,v0,a01); a11=fmaf(pr,v1,a11); a21=fmaf(pr,v2,a21);
            pr = exp2f(fmaf(q2.x,k0,fmaf(q2.y,k1,q2.z*k2)));
            l2+=pr; a02=fmaf(pr,v0,a02); a12=fmaf(pr,v1,a12); a22=fmaf(pr,v2,a22);
            pr = exp2f(fmaf(q3.x,k0,fmaf(q3.y,k1,q3.z*k2)));
            l3+=pr; a03=fmaf(pr,v0,a03); a13=fmaf(pr,v1,a13); a23=fmaf(pr,v2,a23);
        }
    } else {
        // diagonal tile: query j-th of lane is (64*j + lane); key rel = kw+it
        #pragma unroll 4
        for (int it = 0; it < 64; ++it) {
            int kr = kw + it;
            uint4 rec = skv[kw + it];
            float2 f0 = __half22float2(*reinterpret_cast<const __half2*>(&rec.x));
            float2 f1 = __half22float2(*reinterpret_cast<const __half2*>(&rec.y));
            float2 f2 = __half22float2(*reinterpret_cast<const __half2*>(&rec.z));
            float k0 = f0.x, k1 = f0.y, k2 = f1.x;
            float v0 = f1.y, v1 = f2.x, v2 = f2.y;
            float pr;
            pr = exp2f(fmaf(q0.x,k0,fmaf(q0.y,k1,q0.z*k2)));
            pr = (kr <= lane)       ? pr : 0.f;
            l0+=pr; a00=fmaf(pr,v0,a00); a10=fmaf(pr,v1,a10); a20=fmaf(pr,v2,a20);
            pr = exp2f(fmaf(q1.x,k0,fmaf(q1.y,k1,q1.z*k2)));
            pr = (kr <= 64 + lane)  ? pr : 0.f;
            l1+=pr; a01=fmaf(pr,v0,a01); a11=fmaf(pr,v1,a11); a21=fmaf(pr,v2,a21);
            pr = exp2f(fmaf(q2.x,k0,fmaf(q2.y,k1,q2.z*k2)));
            pr = (kr <= 128 + lane) ? pr : 0.f;
            l2+=pr; a02=fmaf(pr,v0,a02); a12=fmaf(pr,v1,a12); a22=fmaf(pr,v2,a22);
            pr = exp2f(fmaf(q3.x,k0,fmaf(q3.y,k1,q3.z*k2)));
            pr = (kr <= 192 + lane) ? pr : 0.f;
            l3+=pr; a03=fmaf(pr,v0,a03); a13=fmaf(pr,v1,a13); a23=fmaf(pr,v2,a23);
        }
    }

    // per-wave partials: spart[wv*256 + 64*j + lane] (16B lane stride: 2-way, free)
    spart[(wv << 8) + lane]       = make_float4(a00, a10, a20, l0);
    spart[(wv << 8) + 64 + lane]  = make_float4(a01, a11, a21, l1);
    spart[(wv << 8) + 128 + lane] = make_float4(a02, a12, a22, l2);
    spart[(wv << 8) + 192 + lane] = make_float4(a03, a13, a23, l3);
    __syncthreads();

    // block reduce across 4 waves; coalesced transposed pbuf store
    float4 p0 = spart[tid];
    float4 p1 = spart[256 + tid];
    float4 p2 = spart[512 + tid];
    float4 p3 = spart[768 + tid];
    float4 acc = make_float4(p0.x+p1.x+p2.x+p3.x, p0.y+p1.y+p2.y+p3.y,
                             p0.z+p1.z+p2.z+p3.z, p0.w+p1.w+p2.w+p3.w);
    p.pbuf[((size_t)bh * 8 + c) * TT + (s << 8) + tid] = acc;
}

// ---------------------------------------------------------------------------
// Kernel B: per-token epilogue. Sum chunk partials (transposed pbuf, coalesced),
// normalize, Wo+residual, LN2, exact GELU FFN, residual, LNf, logits.
// ---------------------------------------------------------------------------
__global__ __launch_bounds__(256) void epi_kernel(P p) {
    int gid = blockIdx.x * 256 + threadIdx.x;
    if (gid >= NTOK) return;
    int t = gid & (TT - 1);
    int b = gid >> 11;
    int s = t >> 8;

    float x[DM];
    int tok = p.idx[gid];
    #pragma unroll
    for (int j = 0; j < TOKD; ++j) x[j]        = p.tok_emb[tok * TOKD + j];
    #pragma unroll
    for (int j = 0; j < POSD; ++j) x[TOKD + j] = p.pos_enc[t * POSD + j];

    float att[AD];
    #pragma unroll
    for (int hh = 0; hh < NH; ++hh) {
        const float4* pp = p.pbuf + ((size_t)(b * NH + hh) * 8) * TT + t;
        float4 acc = pp[0];
        for (int c = 1; c <= s; ++c) {
            float4 e = pp[(size_t)c * TT];
            acc.x += e.x; acc.y += e.y; acc.z += e.z; acc.w += e.w;
        }
        float inv = 1.f / acc.w;
        att[hh*3+0] = acc.x * inv;
        att[hh*3+1] = acc.y * inv;
        att[hh*3+2] = acc.z * inv;
    }

    float xo[DM];
    #pragma unroll
    for (int j = 0; j < DM; ++j) {
        float sacc = x[j];
        #pragma unroll
        for (int a = 0; a < AD; ++a) sacc = fmaf(p.Wo[j * AD + a], att[a], sacc);
        xo[j] = sacc;
    }

    float m = 0.f;
    #pragma unroll
    for (int j = 0; j < DM; ++j) m += xo[j];
    m *= (1.f / DM);
    float v = 0.f;
    #pragma unroll
    for (int j = 0; j < DM; ++j) { float d = xo[j] - m; v += d * d; }
    v *= (1.f / DM);
    float rs = rsqrtf(v + 1e-5f);
    float h2[DM];
    #pragma unroll
    for (int j = 0; j < DM; ++j)
        h2[j] = (xo[j] - m) * rs * p.ln2w[j] + p.ln2b[j];

    float g[FFND];
    #pragma unroll
    for (int cc = 0; cc < FFND; ++cc) {
        float f = p.b1[cc];
        #pragma unroll
        for (int j = 0; j < DM; ++j) f = fmaf(p.W1[cc * DM + j], h2[j], f);
        g[cc] = 0.5f * f * (1.f + erff(f * 0.70710678118654752f));
    }
    float x2[DM];
    #pragma unroll
    for (int j = 0; j < DM; ++j) {
        float sacc = xo[j] + p.b2[j];
        #pragma unroll
        for (int cc = 0; cc < FFND; ++cc) sacc = fmaf(p.W2[j * FFND + cc], g[cc], sacc);
        x2[j] = sacc;
    }

    m = 0.f;
    #pragma unroll
    for (int j = 0; j < DM; ++j) m += x2[j];
    m *= (1.f / DM);
    v = 0.f;
    #pragma unroll
    for (int j = 0; j < DM; ++j) { float d = x2[j] - m; v += d * d; }
    v *= (1.f / DM);
    rs = rsqrtf(v + 1e-5f);
    float y[DM];
    #pragma unroll
    for (int j = 0; j < DM; ++j)
        y[j] = (x2[j] - m) * rs * p.lnfw[j] + p.lnfb[j];

    float t8[TOKD];
    #pragma unroll
    for (int pp = 0; pp < TOKD; ++pp) {
        float sacc = 0.f;
        #pragma unroll
        for (int j = 0; j < DM; ++j) sacc = fmaf(p.Wh[pp * DM + j], y[j], sacc);
        t8[pp] = sacc;
    }
    float* op = p.out + (size_t)gid * VOCAB;
    #pragma unroll
    for (int vcb = 0; vcb < VOCAB; ++vcb) {
        float sacc = 0.f;
        #pragma unroll
        for (int pp = 0; pp < TOKD; ++pp)
            sacc = fmaf(t8[pp], p.tok_emb[vcb * TOKD + pp], sacc);
        op[vcb] = sacc;
    }
}

// ---------------------------------------------------------------------------
extern "C" void kernel_launch(void* const* d_in, const int* in_sizes, int n_in,
                              void* d_out, int out_size, void* d_ws, size_t ws_size,
                              hipStream_t stream) {
    P p;
    p.idx     = (const int*)d_in[0];
    p.tok_emb = (const float*)d_in[1];
    p.pos_enc = (const float*)d_in[2];
    p.Wq      = (const float*)d_in[3];
    p.Wk      = (const float*)d_in[4];
    p.Wv      = (const float*)d_in[5];
    p.Wo      = (const float*)d_in[6];
    p.ln1w    = (const float*)d_in[7];
    p.ln1b    = (const float*)d_in[8];
    p.ln2w    = (const float*)d_in[9];
    p.ln2b    = (const float*)d_in[10];
    p.lnfw    = (const float*)d_in[11];
    p.lnfb    = (const float*)d_in[12];
    p.W1      = (const float*)d_in[13];
    p.b1      = (const float*)d_in[14];
    p.W2      = (const float*)d_in[15];
    p.b2      = (const float*)d_in[16];
    p.Wh      = (const float*)d_in[17];
    p.out     = (float*)d_out;
    p.pbuf    = (float4*)d_ws;   // [32][8][2048] float4 = 8 MB

    attn_kernel<<<NTILE, 256, 0, stream>>>(p);
    epi_kernel<<<NTOK / 256, 256, 0, stream>>>(p);
}